// Round 1
// 287.109 us; speedup vs baseline: 1.0066x; 1.0066x over previous
//
#include <hip/hip_runtime.h>
#include <math.h>

#define EPS 1e-5f

typedef __attribute__((ext_vector_type(8)))  _Float16 half8;   // 8 f16 (4 VGPR)
typedef __attribute__((ext_vector_type(16))) float    floatx16;

__device__ __forceinline__ unsigned short f2h_bits(float f) {
    _Float16 h = (_Float16)f;
    return __builtin_bit_cast(unsigned short, h);
}

// ---------------------------------------------------------------------------
// Fused prepass: one dispatch, block-range dispatch to three roles.
//   blocks [0, nbData)                : data[N][32] fp32 -> dpk[N][32] f16
//   blocks [nbData, nbData+14)        : W[27][32][32] -> f16 B-fragments (wpk)
//   block   nbData+14                 : zero gs1/gs2/gcnt (520 floats)
//   blocks [nbData+15, ...)           : neigh[N][27] -> neighp[N][28]
// ---------------------------------------------------------------------------
__global__ __launch_bounds__(256) void pack_all_kernel(
    const float* __restrict__ data, unsigned short* __restrict__ dpk,
    const float* __restrict__ W, unsigned short* __restrict__ wpk,
    const int* __restrict__ neigh, int* __restrict__ neighp,
    float* __restrict__ gzero, int N, int nbData)
{
    const int b = blockIdx.x;
    const int tid = threadIdx.x;

    if (b < nbData) {
        // ---- data pack: thread = 4 floats -> 4 f16
        const int i = b * 256 + tid;                 // float4 index
        if (i >= N * 8) return;
        const float4 v = ((const float4*)data)[i];
        ushort4 o;
        o.x = f2h_bits(v.x);
        o.y = f2h_bits(v.y);
        o.z = f2h_bits(v.z);
        o.w = f2h_bits(v.w);
        ((ushort4*)dpk)[i] = o;
        return;
    }
    const int wb = b - nbData;
    if (wb < 14) {
        // ---- weight pack: B[k][n], lane l holds n=l&31, k=8*(l>>5)+j.
        // wpk layout: [(tap*2+chunk)*64 + lane] x half8. Tap 27 = zeros.
        const int t = wb * 256 + tid;                // (tap*2+chunk)*64+lane
        const int l = t & 63;
        const int c = (t >> 6) & 1;
        const int k = t >> 7;
        ushort4 o0 = make_ushort4(0, 0, 0, 0), o1 = o0;
        if (k < 27) {
            const int n  = l & 31;
            const int cb = c * 16 + (l >> 5) * 8;    // ci base for this lane
            const float* wp = W + k * 1024 + n;
            o0.x = f2h_bits(wp[(cb + 0) * 32]);
            o0.y = f2h_bits(wp[(cb + 1) * 32]);
            o0.z = f2h_bits(wp[(cb + 2) * 32]);
            o0.w = f2h_bits(wp[(cb + 3) * 32]);
            o1.x = f2h_bits(wp[(cb + 4) * 32]);
            o1.y = f2h_bits(wp[(cb + 5) * 32]);
            o1.z = f2h_bits(wp[(cb + 6) * 32]);
            o1.w = f2h_bits(wp[(cb + 7) * 32]);
        }
        *(ushort4*)(wpk + (size_t)t * 8)     = o0;
        *(ushort4*)(wpk + (size_t)t * 8 + 4) = o1;
        return;
    }
    if (wb == 14) {
        // ---- zero global stats (replaces hipMemsetAsync dispatch)
        if (tid < 520) gzero[tid] = 0.f;
        return;
    }
    // ---- neigh pack: [N][27] -> [N][28] (16 B-aligned rows for int4 loads)
    const int i = (wb - 15) * 256 + tid;
    if (i >= N * 28) return;
    const int n = i / 28;
    const int k = i % 28;
    neighp[i] = neigh[n * 27 + (k < 27 ? k : 26)];
}

// ---------------------------------------------------------------------------
// Deconv via f16 MFMA + GN stats. Block = 512 = 8 waves (was 256/4): the 57 KB
// B-fragment LDS is per-block, so doubling the block doubles waves/CU at the
// same LDS footprint -> 2 blocks/CU = 16 waves/CU (50% nominal vs 20% before).
// The kernel is gather-latency-bound (MfmaUtil 4.6%, VALUBusy 5%, HBM 45%),
// so occupancy is the lever. Inner loop unchanged (proven, 88 VGPR <= 128 cap
// from __launch_bounds__(512,4)).
// Wave = 32 nodes x 32 couts (one 32x32x16 acc chain, 2 MFMA per tap).
// A: 2 x b128 gather per lane per tap, software-pipelined one quad ahead.
// ---------------------------------------------------------------------------
__global__ __launch_bounds__(512, 4) void deconv_stats_kernel(
    const unsigned short* __restrict__ dpk, const unsigned short* __restrict__ wpk,
    const int* __restrict__ nbase, int nstride, int quadok,
    const int* __restrict__ batch_id, float* __restrict__ out,
    float* __restrict__ gs1, float* __restrict__ gs2, float* __restrict__ gcnt,
    int N)
{
    __shared__ unsigned short BW[28 * 2 * 64 * 8];    // 57344 B
    __shared__ float ls1[256];
    __shared__ float ls2[256];
    __shared__ float lcnt[8];

    const int t    = threadIdx.x;                     // 0..511
    const int wv   = t >> 6;                          // 0..7
    const int l    = t & 63;
    const int mrow = l & 31;
    const int half = l >> 5;
    const int wbase = blockIdx.x * 256 + wv * 32;
    const int node  = wbase + mrow;
    const int nc    = node < N ? node : N - 1;

    // stage all B fragments to LDS (coalesced, 7 x 8 KB with 512 threads)
#pragma unroll
    for (int r = 0; r < 7; ++r)
        ((int4*)BW)[r * 512 + t] = ((const int4*)wpk)[r * 512 + t];
    if (t < 256) {
        ls1[t] = 0.f;
        ls2[t] = 0.f;
    }
    if (t < 8) lcnt[t] = 0.f;
    __syncthreads();

    floatx16 acc;
#pragma unroll
    for (int r = 0; r < 16; ++r) acc[r] = 0.f;

    const int* nrow = nbase + (size_t)nc * nstride;
    const int aoff  = half * 8;      // f16 offset: chunk c base = 16c + 8*half

    int4 nq;
    if (quadok) nq = ((const int4*)nrow)[0];
    else { nq.x = nrow[0]; nq.y = nrow[1]; nq.z = nrow[2]; nq.w = nrow[3]; }

    half8 a0, a1, a2, a3, a4, a5, a6, a7;     // current quad: tap j, chunk c -> a(2j+c)
    {
        const unsigned short* r0 = dpk + (size_t)nq.x * 32;
        const unsigned short* r1 = dpk + (size_t)nq.y * 32;
        const unsigned short* r2 = dpk + (size_t)nq.z * 32;
        const unsigned short* r3 = dpk + (size_t)nq.w * 32;
        a0 = *(const half8*)(r0 + aoff);  a1 = *(const half8*)(r0 + 16 + aoff);
        a2 = *(const half8*)(r1 + aoff);  a3 = *(const half8*)(r1 + 16 + aoff);
        a4 = *(const half8*)(r2 + aoff);  a5 = *(const half8*)(r2 + 16 + aoff);
        a6 = *(const half8*)(r3 + aoff);  a7 = *(const half8*)(r3 + 16 + aoff);
    }

    const half8* BL = (const half8*)BW;

#pragma unroll 1
    for (int it = 0; it < 7; ++it) {
        half8 b0, b1, b2, b3, b4, b5, b6, b7;
        if (it < 6) {                 // issue next quad's gathers (latency cover)
            int4 nqn;
            if (quadok) nqn = ((const int4*)nrow)[it + 1];
            else {
                const int kb = (it + 1) * 4;
                nqn.x = nrow[kb];
                nqn.y = nrow[kb + 1];
                nqn.z = nrow[kb + 2];
                nqn.w = nrow[kb + 3 < 27 ? kb + 3 : 26];
            }
            const unsigned short* r0 = dpk + (size_t)nqn.x * 32;
            const unsigned short* r1 = dpk + (size_t)nqn.y * 32;
            const unsigned short* r2 = dpk + (size_t)nqn.z * 32;
            const unsigned short* r3 = dpk + (size_t)nqn.w * 32;
            b0 = *(const half8*)(r0 + aoff);  b1 = *(const half8*)(r0 + 16 + aoff);
            b2 = *(const half8*)(r1 + aoff);  b3 = *(const half8*)(r1 + 16 + aoff);
            b4 = *(const half8*)(r2 + aoff);  b5 = *(const half8*)(r2 + 16 + aoff);
            b6 = *(const half8*)(r3 + aoff);  b7 = *(const half8*)(r3 + 16 + aoff);
        }

        // compute current quad: (tap*2+chunk) = 8*it + (0..7) matches a0..a7
        acc = __builtin_amdgcn_mfma_f32_32x32x16_f16(a0, BL[(8 * it + 0) * 64 + l], acc, 0, 0, 0);
        acc = __builtin_amdgcn_mfma_f32_32x32x16_f16(a1, BL[(8 * it + 1) * 64 + l], acc, 0, 0, 0);
        acc = __builtin_amdgcn_mfma_f32_32x32x16_f16(a2, BL[(8 * it + 2) * 64 + l], acc, 0, 0, 0);
        acc = __builtin_amdgcn_mfma_f32_32x32x16_f16(a3, BL[(8 * it + 3) * 64 + l], acc, 0, 0, 0);
        acc = __builtin_amdgcn_mfma_f32_32x32x16_f16(a4, BL[(8 * it + 4) * 64 + l], acc, 0, 0, 0);
        acc = __builtin_amdgcn_mfma_f32_32x32x16_f16(a5, BL[(8 * it + 5) * 64 + l], acc, 0, 0, 0);
        acc = __builtin_amdgcn_mfma_f32_32x32x16_f16(a6, BL[(8 * it + 6) * 64 + l], acc, 0, 0, 0);
        acc = __builtin_amdgcn_mfma_f32_32x32x16_f16(a7, BL[(8 * it + 7) * 64 + l], acc, 0, 0, 0);

        if (it < 6) {
            a0 = b0; a1 = b1; a2 = b2; a3 = b3;
            a4 = b4; a5 = b5; a6 = b6; a7 = b7;
        }
    }

    // ---- epilogue (proven): C layout col=l&31, row=(r&3)+8(r>>2)+4*half
    const int co = mrow;
#pragma unroll
    for (int r = 0; r < 16; ++r) {
        const int row = (r & 3) + 8 * (r >> 2) + 4 * half;
        const int n = wbase + row;
        if (n < N) out[(size_t)n * 32 + co] = acc[r];
    }

    bool fast = (wbase + 31 < N);
    int bfst = 0;
    if (fast) {
        bfst = batch_id[wbase];
        fast = (bfst == batch_id[wbase + 31]);
    }
    if (fast) {
        float s1 = 0.f, s2 = 0.f;
#pragma unroll
        for (int r = 0; r < 16; ++r) {
            const float v = acc[r];
            s1 += v;
            s2 += v * v;
        }
        atomicAdd(&ls1[bfst * 32 + co], s1);
        atomicAdd(&ls2[bfst * 32 + co], s2);
    } else {
#pragma unroll
        for (int r = 0; r < 16; ++r) {
            const int row = (r & 3) + 8 * (r >> 2) + 4 * half;
            const int n = wbase + row;
            if (n < N) {
                const int b = batch_id[n];
                const float v = acc[r];
                atomicAdd(&ls1[b * 32 + co], v);
                atomicAdd(&ls2[b * 32 + co], v * v);
            }
        }
    }
    if (half == 0) {
        const int n = wbase + mrow;
        if (n < N) atomicAdd(&lcnt[batch_id[n]], 1.0f);
    }
    __syncthreads();

    if (t < 256) {
        float v;
        v = ls1[t]; if (v != 0.f) atomicAdd(&gs1[t], v);
        v = ls2[t]; if (v != 0.f) atomicAdd(&gs2[t], v);
        if (t < 8) { v = lcnt[t]; if (v != 0.f) atomicAdd(&gcnt[t], v); }
    }
}

// ---------------------------------------------------------------------------
// GN finalize + apply + ReLU (unchanged, proven)
// ---------------------------------------------------------------------------
__global__ __launch_bounds__(256) void gn_relu_kernel(
    float* __restrict__ out, const int* __restrict__ batch_id,
    const float* __restrict__ gs1, const float* __restrict__ gs2,
    const float* __restrict__ gcnt, const float* __restrict__ gamma,
    const float* __restrict__ beta, int N)
{
    const int idx = blockIdx.x * 256 + threadIdx.x;
    if (idx >= N * 8) return;
    const int n = idx >> 3;
    const int g = idx & 7;
    const int b = batch_id[n];

    const float cnt  = gcnt[b] * 4.0f;
    const float icnt = 1.0f / (cnt + EPS);
    const float4 s1 = *(const float4*)(gs1 + b * 32 + g * 4);
    const float4 s2 = *(const float4*)(gs2 + b * 32 + g * 4);
    const float S1 = s1.x + s1.y + s1.z + s1.w;
    const float S2 = s2.x + s2.y + s2.z + s2.w;
    const float m   = S1 * icnt;
    const float var = (S2 - 2.0f * m * S1 + cnt * m * m) * icnt;
    const float istd = rsqrtf(var + EPS);

    const float4 gm4 = *(const float4*)(gamma + g * 4);
    const float4 bt4 = *(const float4*)(beta + g * 4);
    float4 h = *(float4*)(out + (size_t)idx * 4);
    h.x = fmaxf((h.x - m) * istd * gm4.x + bt4.x, 0.f);
    h.y = fmaxf((h.y - m) * istd * gm4.y + bt4.y, 0.f);
    h.z = fmaxf((h.z - m) * istd * gm4.z + bt4.z, 0.f);
    h.w = fmaxf((h.w - m) * istd * gm4.w + bt4.w, 0.f);
    *(float4*)(out + (size_t)idx * 4) = h;
}

// ---------------------------------------------------------------------------
extern "C" void kernel_launch(void* const* d_in, const int* in_sizes, int n_in,
                              void* d_out, int out_size, void* d_ws, size_t ws_size,
                              hipStream_t stream) {
    const float* data     = (const float*)d_in[0];   // [N,32]
    const float* weights  = (const float*)d_in[1];   // [27,32,32]
    const float* gamma    = (const float*)d_in[2];   // [32]
    const float* beta     = (const float*)d_in[3];   // [32]
    const int*   neigh    = (const int*)d_in[4];     // [N,27]
    const int*   batch_id = (const int*)d_in[5];     // [N]
    const int N = in_sizes[0] / 32;
    float* out = (float*)d_out;

    // ws layout (bytes):
    //   [0, 2080)                 : gs1[256] gs2[256] gcnt[8]
    //   [4096, +N*64)             : dpk   (N x 32 f16)
    //   [.., +57344)              : wpk   (28*2*64 half8 fragments)
    //   [.., +N*112)              : neighp (N x 28 int)  -- only if ws fits
    char* wsb = (char*)d_ws;
    float* gs1  = (float*)wsb;
    float* gs2  = gs1 + 256;
    float* gcnt = gs1 + 512;
    unsigned short* dpk = (unsigned short*)(wsb + 4096);
    unsigned short* wpk = (unsigned short*)(wsb + 4096 + (size_t)N * 64);
    int* neighp = (int*)(wsb + 4096 + (size_t)N * 64 + 57344);

    const size_t need = 4096 + (size_t)N * 64 + 57344 + (size_t)N * 112;
    const int pack_ok = (ws_size >= need) ? 1 : 0;

    // fused prepass: data pack + w pack + gs zero + (optional) neigh pack
    const int nbData  = (N * 8 + 255) / 256;
    const int nbNeigh = pack_ok ? (N * 28 + 255) / 256 : 0;
    hipLaunchKernelGGL(pack_all_kernel, dim3(nbData + 15 + nbNeigh), dim3(256),
                       0, stream, data, dpk, weights, wpk, neigh, neighp,
                       gs1, N, nbData);

    const int* nbase  = pack_ok ? neighp : neigh;
    const int nstride = pack_ok ? 28 : 27;

    const int nblocks = (N + 255) / 256;
    hipLaunchKernelGGL(deconv_stats_kernel, dim3(nblocks), dim3(512), 0, stream,
                       dpk, wpk, nbase, nstride, pack_ok, batch_id, out,
                       gs1, gs2, gcnt, N);

    const int n8 = N * 8;
    hipLaunchKernelGGL(gn_relu_kernel, dim3((n8 + 255) / 256), dim3(256), 0,
                       stream, out, batch_id, gs1, gs2, gcnt, gamma, beta, N);
}